// Round 7
// baseline (1920.238 us; speedup 1.0000x reference)
//
#include <hip/hip_runtime.h>
#include <hip/hip_bf16.h>
#include <stdint.h>

#define D 64
typedef __hip_bfloat16 bf16;
typedef unsigned short u16;

__device__ __forceinline__ float bf2f(u16 u) { return __uint_as_float(((uint32_t)u) << 16); }
__device__ __forceinline__ float lo16(uint32_t w) { return __uint_as_float(w << 16); }
__device__ __forceinline__ float hi16(uint32_t w) { return __uint_as_float(w & 0xffff0000u); }

template <bool F32>
__device__ __forceinline__ float ld(const void* p, int i) {
    if constexpr (F32) return ((const float*)p)[i];
    else return bf2f(((const u16*)p)[i]);
}

// ---- dtype oracle ----
__global__ __launch_bounds__(256) void detect_kernel(const void* x, const int* ei, int* flags) {
    __shared__ float smax[256];
    __shared__ int sor[256];
    int t = threadIdx.x;
    const u16* xs = (const u16*)x;
    float mx = 0.f;
#pragma unroll
    for (int i = 0; i < 16; ++i) {
        float a = fabsf(bf2f(xs[t * 16 + i]));
        if (!(a == a)) a = 1e30f;
        mx = fmaxf(mx, a);
    }
    int any = 0;
#pragma unroll
    for (int i = 0; i < 8; ++i) any |= ei[2 * (t * 8 + i) + 1];
    smax[t] = mx;
    sor[t] = any;
    __syncthreads();
    for (int s = 128; s > 0; s >>= 1) {
        if (t < s) { smax[t] = fmaxf(smax[t], smax[t + s]); sor[t] |= sor[t + s]; }
        __syncthreads();
    }
    if (t == 0) {
        flags[0] = (smax[0] > 1000.f) ? 1 : 0;
        flags[1] = (sor[0] != 0) ? 1 : 0;
    }
}

// ---- node_transform (round-6 verbatim) ----
template <bool F32>
__device__ __forceinline__ void nt_body(const void* x, const void* Wnt, const void* bnt,
                                        float* h, int N) {
    int gid = blockIdx.x * 256 + threadIdx.x;
    if (gid >= N * D) return;
    int n = gid >> 6, c = gid & 63;
    float acc = ld<F32>(bnt, c);
#pragma unroll
    for (int k = 0; k < 6; ++k)
        acc = fmaf(ld<F32>(x, n * 6 + k), ld<F32>(Wnt, c * 6 + k), acc);
    h[gid] = fmaxf(acc, 0.f);
}
__global__ __launch_bounds__(256) void nt_kernel(const int* flags, const void* x, const void* Wnt,
                                                 const void* bnt, float* h, int N) {
    if (flags[0]) nt_body<true>(x, Wnt, bnt, h, N);
    else          nt_body<false>(x, Wnt, bnt, h, N);
}

// ---- m = h @ weight[layer] (round-6 verbatim) ----
template <bool F32>
__device__ __forceinline__ void m_body(const float* h, const void* W, int woff, float* m, int N) {
    int lane = threadIdx.x & 63;
    int n = blockIdx.x * 4 + (threadIdx.x >> 6);
    if (n >= N) return;
    const float* hrow = h + (size_t)n * D;
    float acc = 0.f;
#pragma unroll
    for (int k = 0; k < D; ++k)
        acc = fmaf(hrow[k], ld<F32>(W, woff + k * D + lane), acc);
    m[(size_t)n * D + lane] = acc;
}
__global__ __launch_bounds__(256) void m_kernel(const int* flags, const float* h, const void* W,
                                                int woff, float* m, int N) {
    if (flags[0]) m_body<true>(h, W, woff, m, N);
    else          m_body<false>(h, W, woff, m, N);
}

// ---- scatter (round-1 verbatim, proven) ----
__global__ __launch_bounds__(256) void scatter_kernel(const int* flags, const float* __restrict__ m,
                                                      const int* __restrict__ ei,
                                                      float* __restrict__ agg, int E, int N) {
    int e = blockIdx.x * 4 + (threadIdx.x >> 6);
    if (e >= E) return;
    int lane = threadIdx.x & 63;
    int src, dst;
    if (flags[1]) { src = ei[e];     dst = ei[E + e]; }
    else          { src = ei[2 * e]; dst = ei[2 * (E + e)]; }
    if ((unsigned)src >= (unsigned)N || (unsigned)dst >= (unsigned)N) return;
    float v = m[(size_t)src * D + lane];
    atomicAdd(&agg[(size_t)dst * D + lane], v);
}

// ---- GRU, bf16 path: round-6 body + LDS-staged weights (broadcast uint4 reads).
//      Staging runs on ALL threads before the single __syncthreads; the n<N
//      guard only masks compute (no thread skips the barrier).
__device__ __forceinline__ void gru_body_bf16(uint32_t* LW, float* LB,
                                              const float* agg, const float* h,
                                              const void* Wih, const void* Whh,
                                              const void* bih, const void* bhh,
                                              float* hout, void* obuf, int N) {
    int t = threadIdx.x;
    {   // stage Wih (6144 dwords) + Whh (6144 dwords) + biases (fp32)
        const uint32_t* wi = (const uint32_t*)Wih;
        const uint32_t* wh = (const uint32_t*)Whh;
#pragma unroll
        for (int i = 0; i < 24; ++i) LW[t + 256 * i] = wi[t + 256 * i];
#pragma unroll
        for (int i = 0; i < 24; ++i) LW[6144 + t + 256 * i] = wh[t + 256 * i];
        if (t < 192) {
            LB[t] = bf2f(((const u16*)bih)[t]);
            LB[192 + t] = bf2f(((const u16*)bhh)[t]);
        }
    }
    __syncthreads();
    int lane = t & 63;
    int sub = t >> 6;
    int n = blockIdx.x * 64 + lane;
    if (n >= N) return;  // no barriers after this point

    float ar[D], hv[D];
    const float4* a4 = (const float4*)(agg + (size_t)n * D);
    const float4* h4 = (const float4*)(h + (size_t)n * D);
#pragma unroll
    for (int i = 0; i < 16; ++i) {
        float4 v = a4[i];
        ar[4 * i] = v.x; ar[4 * i + 1] = v.y; ar[4 * i + 2] = v.z; ar[4 * i + 3] = v.w;
        float4 w = h4[i];
        hv[4 * i] = w.x; hv[4 * i + 1] = w.y; hv[4 * i + 2] = w.z; hv[4 * i + 3] = w.w;
    }
    const uint4* LW4 = (const uint4*)LW;
    int c0 = sub * 16;
#pragma unroll 1
    for (int cc = 0; cc < 16; ++cc) {
        int c = c0 + cc;
        float air = LB[c], aiz = LB[64 + c], ain = LB[128 + c];
        float ahr = LB[192 + c], ahz = LB[256 + c], ahn = LB[320 + c];
        const uint4* wr = LW4 + (c) * 8;            // Wih row c      (r gate)
        const uint4* wz = LW4 + (64 + c) * 8;       // Wih row 64+c   (z gate)
        const uint4* wn = LW4 + (128 + c) * 8;      // Wih row 128+c  (n gate)
        const uint4* vr = LW4 + 1536 + (c) * 8;     // Whh rows
        const uint4* vz = LW4 + 1536 + (64 + c) * 8;
        const uint4* vn = LW4 + 1536 + (128 + c) * 8;
#pragma unroll
        for (int j = 0; j < 8; ++j) {   // elems 8j..8j+7 (uint4 = 4 dwords = 8 bf16)
            uint4 a = wr[j], b = wz[j], d = wn[j];
            uint4 p = vr[j], q = vz[j], s = vn[j];
            air = fmaf(ar[8 * j + 0], lo16(a.x), air); air = fmaf(ar[8 * j + 1], hi16(a.x), air);
            air = fmaf(ar[8 * j + 2], lo16(a.y), air); air = fmaf(ar[8 * j + 3], hi16(a.y), air);
            air = fmaf(ar[8 * j + 4], lo16(a.z), air); air = fmaf(ar[8 * j + 5], hi16(a.z), air);
            air = fmaf(ar[8 * j + 6], lo16(a.w), air); air = fmaf(ar[8 * j + 7], hi16(a.w), air);
            aiz = fmaf(ar[8 * j + 0], lo16(b.x), aiz); aiz = fmaf(ar[8 * j + 1], hi16(b.x), aiz);
            aiz = fmaf(ar[8 * j + 2], lo16(b.y), aiz); aiz = fmaf(ar[8 * j + 3], hi16(b.y), aiz);
            aiz = fmaf(ar[8 * j + 4], lo16(b.z), aiz); aiz = fmaf(ar[8 * j + 5], hi16(b.z), aiz);
            aiz = fmaf(ar[8 * j + 6], lo16(b.w), aiz); aiz = fmaf(ar[8 * j + 7], hi16(b.w), aiz);
            ain = fmaf(ar[8 * j + 0], lo16(d.x), ain); ain = fmaf(ar[8 * j + 1], hi16(d.x), ain);
            ain = fmaf(ar[8 * j + 2], lo16(d.y), ain); ain = fmaf(ar[8 * j + 3], hi16(d.y), ain);
            ain = fmaf(ar[8 * j + 4], lo16(d.z), ain); ain = fmaf(ar[8 * j + 5], hi16(d.z), ain);
            ain = fmaf(ar[8 * j + 6], lo16(d.w), ain); ain = fmaf(ar[8 * j + 7], hi16(d.w), ain);
            ahr = fmaf(hv[8 * j + 0], lo16(p.x), ahr); ahr = fmaf(hv[8 * j + 1], hi16(p.x), ahr);
            ahr = fmaf(hv[8 * j + 2], lo16(p.y), ahr); ahr = fmaf(hv[8 * j + 3], hi16(p.y), ahr);
            ahr = fmaf(hv[8 * j + 4], lo16(p.z), ahr); ahr = fmaf(hv[8 * j + 5], hi16(p.z), ahr);
            ahr = fmaf(hv[8 * j + 6], lo16(p.w), ahr); ahr = fmaf(hv[8 * j + 7], hi16(p.w), ahr);
            ahz = fmaf(hv[8 * j + 0], lo16(q.x), ahz); ahz = fmaf(hv[8 * j + 1], hi16(q.x), ahz);
            ahz = fmaf(hv[8 * j + 2], lo16(q.y), ahz); ahz = fmaf(hv[8 * j + 3], hi16(q.y), ahz);
            ahz = fmaf(hv[8 * j + 4], lo16(q.z), ahz); ahz = fmaf(hv[8 * j + 5], hi16(q.z), ahz);
            ahz = fmaf(hv[8 * j + 6], lo16(q.w), ahz); ahz = fmaf(hv[8 * j + 7], hi16(q.w), ahz);
            ahn = fmaf(hv[8 * j + 0], lo16(s.x), ahn); ahn = fmaf(hv[8 * j + 1], hi16(s.x), ahn);
            ahn = fmaf(hv[8 * j + 2], lo16(s.y), ahn); ahn = fmaf(hv[8 * j + 3], hi16(s.y), ahn);
            ahn = fmaf(hv[8 * j + 4], lo16(s.z), ahn); ahn = fmaf(hv[8 * j + 5], hi16(s.z), ahn);
            ahn = fmaf(hv[8 * j + 6], lo16(s.w), ahn); ahn = fmaf(hv[8 * j + 7], hi16(s.w), ahn);
        }
        float r = 1.f / (1.f + __expf(-(air + ahr)));
        float z = 1.f / (1.f + __expf(-(aiz + ahz)));
        float nx = ain + r * ahn;
        float nn = 1.f - 2.f / (1.f + __expf(2.f * nx));  // tanh, overflow-safe
        float hcur = h[(size_t)n * D + c];                // reload (avoids hv[c] spill)
        float hn = (1.f - z) * nn + z * hcur;
        if (hout) hout[(size_t)n * D + c] = hn;
        else ((bf16*)obuf)[(size_t)n * D + c] = __float2bfloat16(hn);
    }
}

// F32 fallback: round-6 body verbatim (no LDS)
__device__ __forceinline__ void gru_body_f32(const float* agg, const float* h,
                                             const void* Wih, const void* Whh,
                                             const void* bih, const void* bhh,
                                             float* hout, void* obuf, int N) {
    int lane = threadIdx.x & 63;
    int sub = threadIdx.x >> 6;
    int n = blockIdx.x * 64 + lane;
    if (n >= N) return;
    float ar[D], hv[D];
    const float4* a4 = (const float4*)(agg + (size_t)n * D);
    const float4* h4 = (const float4*)(h + (size_t)n * D);
#pragma unroll
    for (int i = 0; i < 16; ++i) {
        float4 v = a4[i];
        ar[4 * i] = v.x; ar[4 * i + 1] = v.y; ar[4 * i + 2] = v.z; ar[4 * i + 3] = v.w;
        float4 w = h4[i];
        hv[4 * i] = w.x; hv[4 * i + 1] = w.y; hv[4 * i + 2] = w.z; hv[4 * i + 3] = w.w;
    }
    int c0 = sub * 16;
#pragma unroll 1
    for (int cc = 0; cc < 16; ++cc) {
        int c = c0 + cc;
        float air = ld<true>(bih, c), aiz = ld<true>(bih, 64 + c), ain = ld<true>(bih, 128 + c);
        float ahr = ld<true>(bhh, c), ahz = ld<true>(bhh, 64 + c), ahn = ld<true>(bhh, 128 + c);
#pragma unroll
        for (int k = 0; k < D; ++k) {
            air = fmaf(ar[k], ld<true>(Wih, c * D + k), air);
            aiz = fmaf(ar[k], ld<true>(Wih, (64 + c) * D + k), aiz);
            ain = fmaf(ar[k], ld<true>(Wih, (128 + c) * D + k), ain);
            ahr = fmaf(hv[k], ld<true>(Whh, c * D + k), ahr);
            ahz = fmaf(hv[k], ld<true>(Whh, (64 + c) * D + k), ahz);
            ahn = fmaf(hv[k], ld<true>(Whh, (128 + c) * D + k), ahn);
        }
        float r = 1.f / (1.f + __expf(-(air + ahr)));
        float z = 1.f / (1.f + __expf(-(aiz + ahz)));
        float nx = ain + r * ahn;
        float nn = 1.f - 2.f / (1.f + __expf(2.f * nx));
        float hcur = h[(size_t)n * D + c];
        float hn = (1.f - z) * nn + z * hcur;
        if (hout) hout[(size_t)n * D + c] = hn;
        else ((float*)obuf)[(size_t)n * D + c] = hn;
    }
}

__global__ __launch_bounds__(256, 1) void gru_kernel(const int* flags, const float* agg, const float* h,
                                                     const void* Wih, const void* Whh,
                                                     const void* bih, const void* bhh,
                                                     float* hout, void* obuf, int N) {
    __shared__ alignas(16) uint32_t LW[12288];  // Wih+Whh as bf16-pair dwords (48 KB)
    __shared__ float LB[384];                   // biases fp32
    if (flags[0]) gru_body_f32(agg, h, Wih, Whh, bih, bhh, hout, obuf, N);
    else          gru_body_bf16(LW, LB, agg, h, Wih, Whh, bih, bhh, hout, obuf, N);
}

extern "C" void kernel_launch(void* const* d_in, const int* in_sizes, int n_in,
                              void* d_out, int out_size, void* d_ws, size_t ws_size,
                              hipStream_t stream) {
    const void* x   = d_in[0];
    const int*  ei  = (const int*)d_in[1];
    const void* Wnt = d_in[4];
    const void* bnt = d_in[5];
    const void* Wt  = d_in[6];
    const void* Wih = d_in[7];
    const void* Whh = d_in[8];
    const void* bih = d_in[9];
    const void* bhh = d_in[10];

    int N = in_sizes[0] / 6;
    int E = in_sizes[1] / 2;

    int* flags = (int*)d_ws;
    float* B0 = (float*)((char*)d_ws + 256);
    float* B1 = B0 + (size_t)N * D;
    float* B2 = B1 + (size_t)N * D;

    detect_kernel<<<1, 256, 0, stream>>>(x, ei, flags);
    nt_kernel<<<(N * D + 255) / 256, 256, 0, stream>>>(flags, x, Wnt, bnt, B0, N);

    float* h = B0;
    float* mbuf = B1;
    float* agg = B2;
    for (int layer = 0; layer < 3; ++layer) {
        m_kernel<<<(N + 3) / 4, 256, 0, stream>>>(flags, h, Wt, layer * D * D, mbuf, N);
        hipMemsetAsync(agg, 0, (size_t)N * D * sizeof(float), stream);
        scatter_kernel<<<(E + 3) / 4, 256, 0, stream>>>(flags, mbuf, ei, agg, E, N);
        bool last = (layer == 2);
        gru_kernel<<<(N + 63) / 64, 256, 0, stream>>>(flags, agg, h, Wih, Whh, bih, bhh,
                                                      last ? nullptr : mbuf,
                                                      last ? d_out : nullptr, N);
        float* t = h; h = mbuf; mbuf = t;
    }
}